// Round 12
// baseline (190.632 us; speedup 1.0000x reference)
//
#include <hip/hip_runtime.h>
#include <stdint.h>

#define B_ 4
#define C_ 256
#define N_ 4096
#define JS 4          // j-splits

typedef unsigned short u16;
typedef __attribute__((ext_vector_type(4))) float f32x4;
typedef __attribute__((ext_vector_type(16))) float f32x16;
typedef __attribute__((ext_vector_type(8))) short bf16x8;
typedef __attribute__((ext_vector_type(4))) short u16x4;
typedef __attribute__((ext_vector_type(4))) int i32x4;

__device__ __forceinline__ u16 f2bf(float f) {
    uint32_t u = __float_as_uint(f);
    u += 0x7fffu + ((u >> 16) & 1u);
    return (u16)(u >> 16);
}
__device__ __forceinline__ float bf2f(u16 v) {
    uint32_t u = ((uint32_t)v) << 16;
    return __uint_as_float(u);
}
__device__ __forceinline__ uint32_t pkbf(float a, float b) {
    uint32_t ua = __float_as_uint(a) + 0x8000u;
    uint32_t ub = __float_as_uint(b) + 0x8000u;
    return (ua >> 16) | (ub & 0xffff0000u);
}

__device__ __forceinline__ float fexp2(float x) {
#if defined(__has_builtin)
#if __has_builtin(__builtin_amdgcn_exp2f)
    return __builtin_amdgcn_exp2f(x);
#else
    return exp2f(x);
#endif
#else
    return exp2f(x);
#endif
}

#if defined(__has_builtin)
#if __has_builtin(__builtin_amdgcn_global_load_lds)
#define HAVE_GLL 1
#endif
#endif

#ifdef HAVE_GLL
// DMA 16B/lane: global per-lane addr -> wave-uniform LDS base + lane*16
__device__ __forceinline__ void g2l16(const u16* g, u16* lbase, int lane) {
    (void)lane;  // HW applies lane*16 on the LDS side
    __builtin_amdgcn_global_load_lds(
        (__attribute__((address_space(1))) void*)(uintptr_t)g,
        (__attribute__((address_space(3))) void*)lbase, 16, 0, 0);
}
#else
__device__ __forceinline__ void g2l16(const u16* g, u16* lbase, int lane) {
    *(i32x4*)(lbase + lane * 8) = *(const i32x4*)g;
}
#endif

// ---------------- Stage 0: W fp32 -> bf16, fragment-order layout ----------------
// Wb layout: [mat(3)][quad(4)][half(2)][ks(16)][h(2)][l31(32)][e(8)].
__global__ __launch_bounds__(256) void wconv_kernel(
    const float* __restrict__ Wq, const float* __restrict__ Wk,
    const float* __restrict__ Wv, u16* __restrict__ Wb) {
    int id = blockIdx.x * 256 + threadIdx.x;      // 49152 threads x 4 elems
    int base = id << 2;
    const float* src = (base < 65536) ? Wq : ((base < 131072) ? Wk : Wv);
    int within = base & 65535;
    int mat = base >> 16;
    int o = within >> 8;
    int c = within & 255;                          // 4-aligned
    f32x4 v = *(const f32x4*)(src + within);
    int dst = ((((mat << 2) | (o >> 6)) * 2 + ((o >> 5) & 1)) * 16 + (c >> 4)) * 512
              + (((c >> 3) & 1) << 8) + ((o & 31) << 3) + (c & 7);
    u16x4 pv;
    pv[0] = (short)f2bf(v[0]);
    pv[1] = (short)f2bf(v[1]);
    pv[2] = (short)f2bf(v[2]);
    pv[3] = (short)f2bf(v[3]);
    *(u16x4*)&Wb[dst] = pv;
}

// ---------------- Stage 1: QKV projection, fused 3-mat, 64-n tiles ----------------
// Grid 256 (= #CUs), 512 threads (8 waves), 1 block/CU, 142KB LDS.
// MEASUREMENT ROUND: this kernel is launched TWICE (idempotent) so that
// delta(total) vs R11 = qkv duration + 1 launch. Decides qkv-redesign vs
// gap-fusion endgame.
__global__ __launch_bounds__(512, 2) void qkv_kernel(
    const float* __restrict__ x, const u16* __restrict__ Wb,
    const float* __restrict__ bq, const float* __restrict__ bk,
    const float* __restrict__ bv,
    u16* __restrict__ Qt, u16* __restrict__ Kt, u16* __restrict__ Vt) {
    const int XTS = 264;                       // 528B rows: 16B-aligned, bank-rot 4
    const int TQS = 280;                       // 560B rows: 16B-aligned
    const int TVS = 72;                        // 144B rows: 16B-aligned
    __shared__ __align__(16) u16 xT[64 * XTS];     // 33.8 KB  [n][c]
    __shared__ __align__(16) u16 tqA[64 * TQS];    // 35.8 KB  Q: [n][o]
    __shared__ __align__(16) u16 tqB[64 * TQS];    // 35.8 KB  K: [n][o]
    __shared__ __align__(16) u16 tv[256 * TVS];    // 36.9 KB  V: [o][n]

    int blk = blockIdx.x;
    int n0  = (blk & 63) << 6;
    int b   = blk >> 6;
    int tid = threadIdx.x;         // 0..511
    int lane = tid & 63;
    int w = tid >> 6;              // 0..7
    int wq = w & 3;                // o-quadrant
    int nh = w >> 2;               // n-half
    int l31 = lane & 31;
    int h = lane >> 5;

    {   // stage xT: x[b][c][n0..n0+64) fp32 -> xT[n][c] bf16 (transpose)
        int c0 = tid >> 3;                 // 0..63
        int nq = (tid & 7) << 2;           // 0..28
        const float* xb = x + ((size_t)b * C_ + c0) * N_ + n0 + nq;
        #pragma unroll
        for (int p = 0; p < 4; ++p) {
            f32x4 v0 = *(const f32x4*)(xb + (size_t)64 * N_ * p);
            f32x4 v1 = *(const f32x4*)(xb + (size_t)64 * N_ * p + 32);
            int cc = c0 + 64 * p;
            #pragma unroll
            for (int k = 0; k < 4; ++k) {
                xT[(nq + k) * XTS + cc]      = f2bf(v0[k]);
                xT[(32 + nq + k) * XTS + cc] = f2bf(v1[k]);
            }
        }
    }
    __syncthreads();

    bf16x8 xf[16];
    #pragma unroll
    for (int ks = 0; ks < 16; ++ks)
        xf[ks] = *(const bf16x8*)(&xT[(32 * nh + l31) * XTS + 16 * ks + 8 * h]);

    // ---- Q and K: D[m=n][n'=o] -> LDS [n][o] ----
    #pragma unroll
    for (int mat = 0; mat < 2; ++mat) {
        const float* bias = mat ? bk : bq;
        u16* tq = mat ? tqB : tqA;
        f32x16 acc0, acc1;
        #pragma unroll
        for (int r = 0; r < 16; ++r) { acc0[r] = 0.f; acc1[r] = 0.f; }
        const u16* wA = Wb + ((size_t)((mat * 4 + wq) * 2 + 0)) * 8192 + (size_t)lane * 8;
        const u16* wB = wA + 8192;
        #pragma unroll
        for (int ks = 0; ks < 16; ++ks) {
            bf16x8 wf0 = *(const bf16x8*)(wA + 512 * ks);
            bf16x8 wf1 = *(const bf16x8*)(wB + 512 * ks);
            acc0 = __builtin_amdgcn_mfma_f32_32x32x16_bf16(xf[ks], wf0, acc0, 0, 0, 0);
            acc1 = __builtin_amdgcn_mfma_f32_32x32x16_bf16(xf[ks], wf1, acc1, 0, 0, 0);
        }
        #pragma unroll
        for (int ot = 0; ot < 2; ++ot) {
            const f32x16& a = ot ? acc1 : acc0;
            int o = 64 * wq + 32 * ot + l31;
            float bo = bias[o];
            #pragma unroll
            for (int g = 0; g < 4; ++g)
                #pragma unroll
                for (int r = 0; r < 4; ++r) {
                    int n = 32 * nh + 8 * g + 4 * h + r;   // 0..63
                    tq[n * TQS + o] = f2bf(a[4 * g + r] + bo);
                }
        }
    }

    // ---- V: D[m=o][n'=n] -> LDS [o][n] ----
    {
        f32x16 acc0, acc1;
        #pragma unroll
        for (int r = 0; r < 16; ++r) { acc0[r] = 0.f; acc1[r] = 0.f; }
        const u16* wA = Wb + ((size_t)((2 * 4 + wq) * 2 + 0)) * 8192 + (size_t)lane * 8;
        const u16* wB = wA + 8192;
        #pragma unroll
        for (int ks = 0; ks < 16; ++ks) {
            bf16x8 wf0 = *(const bf16x8*)(wA + 512 * ks);
            bf16x8 wf1 = *(const bf16x8*)(wB + 512 * ks);
            acc0 = __builtin_amdgcn_mfma_f32_32x32x16_bf16(wf0, xf[ks], acc0, 0, 0, 0);
            acc1 = __builtin_amdgcn_mfma_f32_32x32x16_bf16(wf1, xf[ks], acc1, 0, 0, 0);
        }
        #pragma unroll
        for (int mt = 0; mt < 2; ++mt) {
            const f32x16& a = mt ? acc1 : acc0;
            #pragma unroll
            for (int g = 0; g < 4; ++g)
                #pragma unroll
                for (int r = 0; r < 4; ++r) {
                    int o = 64 * wq + 32 * mt + 8 * g + 4 * h + r;
                    tv[o * TVS + 32 * nh + l31] = f2bf(a[4 * g + r] + bv[o]);
                }
        }
    }
    __syncthreads();

    // ---- vector store phase (16B granules) ----
    {   // Q/K: thread -> row n = tid>>3 (0..63), chunks ch = (tid&7)+8i2 (128B/8 lanes)
        int n = tid >> 3;
        size_t row = ((size_t)b * N_ + n0 + n) * C_;
        #pragma unroll
        for (int i2 = 0; i2 < 4; ++i2) {
            int ch = (tid & 7) + 8 * i2;
            bf16x8 vq = *(const bf16x8*)&tqA[n * TQS + ch * 8];
            *(bf16x8*)&Qt[row + ch * 8] = vq;
            int sk = ch ^ (n & 31);   // Kt swizzle: dest chunk ch <- src o-chunk ch^(n&31)
            bf16x8 vk = *(const bf16x8*)&tqB[n * TQS + sk * 8];
            *(bf16x8*)&Kt[row + ch * 8] = vk;
        }
    }
    {   // V: thread -> n-chunk k = tid&7, rows o = (tid>>3)+64j (128B/8 lanes)
        int k = tid & 7;
        #pragma unroll
        for (int j = 0; j < 4; ++j) {
            int o = (tid >> 3) + 64 * j;
            bf16x8 vv = *(const bf16x8*)&tv[o * TVS + k * 8];
            int cd = k ^ (o & 7);     // chunk swizzle, 16B granularity, 64-aligned tile
            *(bf16x8*)&Vt[((size_t)b * C_ + o) * N_ + n0 + cd * 8] = vv;
        }
    }
}

// ---------------- Stage 2: flash attention, 4-wave blocks, 2 blocks/CU ----------------
// Grid 512 = 32 i-tiles(128) x 4 b x 4 s. 2 blocks/CU (64KB LDS each), 8 waves/CU.
// Split-phase staging: K-DMA(jt+1) issued after S^T barrier (hides under
// softmax+PV); only V-DMA latency exposed at the end-of-iter drain.
// NOTE: register budget is EXACTLY full (128 VGPR + 128 AGPR = 2 waves/SIMD hard
// cap). R1 restructure spilled; R3 device-fence merge cost +120us; R9 K-from-L2
// cost 2x (per-wave operand redundancy must be LDS-served).
__device__ __forceinline__ void stageK_4w(const u16* Kb, int j0, u16* ksd,
                                          int w, int lane) {
    const u16* kg = Kb + (size_t)(j0 + 16 * w) * C_ + lane * 8;
    u16* kdb = ksd + 16 * w * 256;
    #pragma unroll
    for (int rr = 0; rr < 8; ++rr)
        g2l16(kg + rr * 512, kdb + rr * 512, lane);
}
__device__ __forceinline__ void stageV_4w(const u16* Vb, int j0, u16* vsd,
                                          int w, int lane) {
    const u16* vg = Vb + (size_t)(64 * w + (lane >> 3)) * N_ + j0 + (lane & 7) * 8;
    u16* vdb = vsd + 64 * w * 64;
    #pragma unroll
    for (int rr = 0; rr < 8; ++rr)
        g2l16(vg + (size_t)8 * rr * N_, vdb + rr * 512, lane);
}

__global__ __launch_bounds__(256, 2) void attn_kernel(
    const u16* __restrict__ Qt, const u16* __restrict__ Kt,
    const u16* __restrict__ Vt, u16* __restrict__ Op,
    float* __restrict__ lArr) {
    __shared__ __align__(16) u16 Ksh[64 * 256];   // 32KB, swizzled rows
    __shared__ __align__(16) u16 Vsh[256 * 64];   // 32KB, swizzled rows

    int blk = blockIdx.x;
    int it = blk & 31;
    int b  = (blk >> 5) & 3;
    int s  = blk >> 7;                 // 0..3
    int i0 = it << 7;                  // 128-row i-tile
    int tid = threadIdx.x;
    int lane = tid & 63;
    int w = tid >> 6;                  // 0..3
    int l31 = lane & 31;
    int h = lane >> 5;

    // Q B-frags from linear Qt: n=i=l31 (wave strip i0+32w), k=c=16ks+8h+e
    bf16x8 qf[16];
    {
        const u16* qrow = Qt + ((size_t)b * N_ + i0 + 32 * w + l31) * C_ + 8 * h;
        #pragma unroll
        for (int ks = 0; ks < 16; ++ks) qf[ks] = *(const bf16x8*)(qrow + 16 * ks);
    }

    f32x16 oacc[8];
    #pragma unroll
    for (int mt = 0; mt < 8; ++mt)
        #pragma unroll
        for (int r = 0; r < 16; ++r) oacc[mt][r] = 0.f;
    float l_run = 0.f;

    const float sconst = 0.0625f * 1.44269504088896340736f;
    const u16* Kb = Kt + (size_t)b * N_ * C_;
    const u16* Vb = Vt + (size_t)b * C_ * N_;
    int jbase = s * (N_ / JS);
    const int NT = N_ / (64 * JS);     // 16

    // prologue: fill both buffers for tile 0
    stageK_4w(Kb, jbase, Ksh, w, lane);
    stageV_4w(Vb, jbase, Vsh, w, lane);
    __syncthreads();                   // drains DMA (implicit vmcnt 0)

    for (int jt = 0; jt < NT; ++jt) {
        int jn = jbase + (jt + 1) * 64;

        // S^T = K·Q^T : D[m=j][n=i]
        f32x16 st0, st1;
        #pragma unroll
        for (int r = 0; r < 16; ++r) { st0[r] = 0.f; st1[r] = 0.f; }
        __builtin_amdgcn_s_setprio(1);
        #pragma unroll
        for (int ks = 0; ks < 16; ++ks) {
            int kc = ((2 * ks + h) ^ l31) << 3;   // (32+l31)&31 == l31: same offset
            bf16x8 kf0 = *(const bf16x8*)(Ksh + l31 * 256 + kc);
            bf16x8 kf1 = *(const bf16x8*)(Ksh + (32 + l31) * 256 + kc);
            st0 = __builtin_amdgcn_mfma_f32_32x32x16_bf16(kf0, qf[ks], st0, 0, 0, 0);
            st1 = __builtin_amdgcn_mfma_f32_32x32x16_bf16(kf1, qf[ks], st1, 0, 0, 0);
        }
        __builtin_amdgcn_s_setprio(0);

        // K(jt) consumed -> issue K-DMA for jt+1; hides under softmax + PV
        __syncthreads();
        if (jt + 1 < NT) stageK_4w(Kb, jn, Ksh, w, lane);

        // softmax numerators, m=0; i = l31 per-lane, partner = lane^32
        float psum = 0.f;
        uint32_t pd[16];
        #pragma unroll
        for (int u = 0; u < 8; ++u) {
            const f32x16& stv = (u < 4) ? st0 : st1;
            int g = u & 3;
            #pragma unroll
            for (int d = 0; d < 2; ++d) {
                float p0 = fexp2(stv[4 * g + 2 * d + 0] * sconst);
                float p1 = fexp2(stv[4 * g + 2 * d + 1] * sconst);
                psum += p0 + p1;
                pd[u * 2 + d] = pkbf(p0, p1);
            }
        }
        psum += __shfl_xor(psum, 32);
        l_run += psum;

        // P: C/D -> B-operand frags via lane^32 quad exchange
        bf16x8 pf[4];
        #pragma unroll
        for (int ks2 = 0; ks2 < 4; ++ks2) {
            uint32_t oA0 = pd[4 * ks2 + 0], oA1 = pd[4 * ks2 + 1];
            uint32_t oB0 = pd[4 * ks2 + 2], oB1 = pd[4 * ks2 + 3];
            uint32_t sn0 = h ? oA0 : oB0, sn1 = h ? oA1 : oB1;
            uint32_t rc0 = (uint32_t)__shfl_xor((int)sn0, 32);
            uint32_t rc1 = (uint32_t)__shfl_xor((int)sn1, 32);
            uint32_t ow0 = h ? oB0 : oA0, ow1 = h ? oB1 : oA1;
            i32x4 fr;
            fr[0] = (int)(h ? rc0 : ow0);
            fr[1] = (int)(h ? rc1 : ow1);
            fr[2] = (int)(h ? ow0 : rc0);
            fr[3] = (int)(h ? ow1 : rc1);
            pf[ks2] = *(bf16x8*)&fr;
        }

        // O += V·P : D[m=c][n=i]; vf swizzled chunk' = (2ks2+h) ^ (l31&7)
        __builtin_amdgcn_s_setprio(1);
        #pragma unroll
        for (int ks2 = 0; ks2 < 4; ++ks2) {
            int vc = ((2 * ks2 + h) ^ (l31 & 7)) << 3;
            #pragma unroll
            for (int mt = 0; mt < 8; ++mt) {
                bf16x8 vf = *(const bf16x8*)(Vsh + (32 * mt + l31) * 64 + vc);
                oacc[mt] = __builtin_amdgcn_mfma_f32_32x32x16_bf16(vf, pf[ks2], oacc[mt], 0, 0, 0);
            }
        }
        __builtin_amdgcn_s_setprio(0);

        // V(jt) consumed -> issue V-DMA for jt+1, then drain both for next iter
        if (jt + 1 < NT) {
            __syncthreads();
            stageV_4w(Vb, jn, Vsh, w, lane);
            __syncthreads();           // drains K- and V-DMA (implicit vmcnt 0)
        }
    }

    // epilogue: unnormalized partial O + l
    int i = i0 + 32 * w + l31;
    u16* ob = Op + ((size_t)(s * B_ + b) * C_) * N_ + i;
    #pragma unroll
    for (int mt = 0; mt < 8; ++mt)
        #pragma unroll
        for (int g = 0; g < 4; ++g)
            #pragma unroll
            for (int r = 0; r < 4; ++r) {
                int c = 32 * mt + 8 * g + r + 4 * h;
                ob[(size_t)c * N_] = f2bf(oacc[mt][4 * g + r]);
            }
    if (h == 0) lArr[(size_t)(s * B_ + b) * N_ + i] = l_run;
}

// ---------------- Stage 3: merge splits + residual (vectorized) ----------------
__global__ __launch_bounds__(256) void merge_kernel(
    const float* __restrict__ x, const u16* __restrict__ Op,
    const float* __restrict__ lArr, float* __restrict__ out) {
    __shared__ float rLs[64];
    int blk = blockIdx.x;
    int cg = blk & 3;
    int ic = (blk >> 2) & 63;
    int b  = blk >> 8;
    int i0 = ic << 6;
    int tid = threadIdx.x;

    if (tid < 64) {
        float L = 0.f;
        #pragma unroll
        for (int s = 0; s < JS; ++s) L += lArr[(size_t)(s * B_ + b) * N_ + i0 + tid];
        rLs[tid] = 1.0f / L;
    }
    __syncthreads();

    int i8 = (tid & 7) << 3;                 // 8 i's
    int c  = (cg << 6) + ((tid >> 3) << 1);  // 2 c's
    f32x4 rl0 = *(const f32x4*)&rLs[i8];
    f32x4 rl1 = *(const f32x4*)&rLs[i8 + 4];

    #pragma unroll
    for (int cc = 0; cc < 2; ++cc) {
        size_t xoff = ((size_t)b * C_ + c + cc) * N_ + i0 + i8;
        float acc[8];
        #pragma unroll
        for (int e = 0; e < 8; ++e) acc[e] = 0.f;
        #pragma unroll
        for (int s = 0; s < JS; ++s) {
            bf16x8 o = *(const bf16x8*)&Op[((size_t)(s * B_ + b) * C_ + c + cc) * N_ + i0 + i8];
            #pragma unroll
            for (int e = 0; e < 8; ++e) acc[e] += bf2f((u16)o[e]);
        }
        f32x4 xv0 = *(const f32x4*)&x[xoff];
        f32x4 xv1 = *(const f32x4*)&x[xoff + 4];
        f32x4 o0, o1;
        #pragma unroll
        for (int e = 0; e < 4; ++e) {
            o0[e] = fmaf(acc[e], rl0[e], xv0[e]);
            o1[e] = fmaf(acc[e + 4], rl1[e], xv1[e]);
        }
        *(f32x4*)&out[xoff] = o0;
        *(f32x4*)&out[xoff + 4] = o1;
    }
}

extern "C" void kernel_launch(void* const* d_in, const int* in_sizes, int n_in,
                              void* d_out, int out_size, void* d_ws, size_t ws_size,
                              hipStream_t stream) {
    const float* x  = (const float*)d_in[0];
    const float* Wq = (const float*)d_in[1];
    const float* bq = (const float*)d_in[2];
    const float* Wk = (const float*)d_in[3];
    const float* bk = (const float*)d_in[4];
    const float* Wv = (const float*)d_in[5];
    const float* bv = (const float*)d_in[6];
    float* out = (float*)d_out;

    u16* Wb = (u16*)d_ws;
    u16* Qt = Wb + 3 * 65536;                     // [B][N][C] linear
    u16* Kt = Qt + (size_t)B_ * N_ * C_;          // [B][N][C] swizzled
    u16* Vt = Kt + (size_t)B_ * N_ * C_;          // [B][C][N] swizzled
    u16* Op = Vt + (size_t)B_ * N_ * C_;          // [JS][B][C][N]
    float* lArr = (float*)(Op + (size_t)JS * B_ * C_ * N_);

    wconv_kernel<<<192, 256, 0, stream>>>(Wq, Wk, Wv, Wb);
    qkv_kernel<<<256, 512, 0, stream>>>(x, Wb, bq, bk, bv, Qt, Kt, Vt);
    // MEASUREMENT: duplicate qkv dispatch (idempotent). delta(total) vs R11
    // = qkv duration + ~2us launch. Remove this line to restore R11-best.
    qkv_kernel<<<256, 512, 0, stream>>>(x, Wb, bq, bk, bv, Qt, Kt, Vt);
    attn_kernel<<<512, 256, 0, stream>>>(Qt, Kt, Vt, Op, lArr);
    merge_kernel<<<1024, 256, 0, stream>>>(x, Op, lArr, out);
}

// Round 13
// 175.657 us; speedup vs baseline: 1.0853x; 1.0853x over previous
//
#include <hip/hip_runtime.h>
#include <stdint.h>

#define B_ 4
#define C_ 256
#define N_ 4096
#define JS 4          // j-splits

typedef unsigned short u16;
typedef __attribute__((ext_vector_type(4))) float f32x4;
typedef __attribute__((ext_vector_type(16))) float f32x16;
typedef __attribute__((ext_vector_type(8))) short bf16x8;
typedef __attribute__((ext_vector_type(4))) short u16x4;
typedef __attribute__((ext_vector_type(4))) int i32x4;

__device__ __forceinline__ u16 f2bf(float f) {
    uint32_t u = __float_as_uint(f);
    u += 0x7fffu + ((u >> 16) & 1u);
    return (u16)(u >> 16);
}
__device__ __forceinline__ float bf2f(u16 v) {
    uint32_t u = ((uint32_t)v) << 16;
    return __uint_as_float(u);
}
__device__ __forceinline__ uint32_t pkbf(float a, float b) {
    uint32_t ua = __float_as_uint(a) + 0x8000u;
    uint32_t ub = __float_as_uint(b) + 0x8000u;
    return (ua >> 16) | (ub & 0xffff0000u);
}

__device__ __forceinline__ float fexp2(float x) {
#if defined(__has_builtin)
#if __has_builtin(__builtin_amdgcn_exp2f)
    return __builtin_amdgcn_exp2f(x);
#else
    return exp2f(x);
#endif
#else
    return exp2f(x);
#endif
}

#if defined(__has_builtin)
#if __has_builtin(__builtin_amdgcn_global_load_lds)
#define HAVE_GLL 1
#endif
#endif

#ifdef HAVE_GLL
// DMA 16B/lane: global per-lane addr -> wave-uniform LDS base + lane*16
__device__ __forceinline__ void g2l16(const u16* g, u16* lbase, int lane) {
    (void)lane;  // HW applies lane*16 on the LDS side
    __builtin_amdgcn_global_load_lds(
        (__attribute__((address_space(1))) void*)(uintptr_t)g,
        (__attribute__((address_space(3))) void*)lbase, 16, 0, 0);
}
#else
__device__ __forceinline__ void g2l16(const u16* g, u16* lbase, int lane) {
    *(i32x4*)(lbase + lane * 8) = *(const i32x4*)g;
}
#endif

// ---------------- Stage 0: W fp32 -> bf16, fragment-order layout ----------------
// Wb layout: [mat(3)][quad(4)][half(2)][ks(16)][h(2)][l31(32)][e(8)].
__global__ __launch_bounds__(256) void wconv_kernel(
    const float* __restrict__ Wq, const float* __restrict__ Wk,
    const float* __restrict__ Wv, u16* __restrict__ Wb) {
    int id = blockIdx.x * 256 + threadIdx.x;      // 49152 threads x 4 elems
    int base = id << 2;
    const float* src = (base < 65536) ? Wq : ((base < 131072) ? Wk : Wv);
    int within = base & 65535;
    int mat = base >> 16;
    int o = within >> 8;
    int c = within & 255;                          // 4-aligned
    f32x4 v = *(const f32x4*)(src + within);
    int dst = ((((mat << 2) | (o >> 6)) * 2 + ((o >> 5) & 1)) * 16 + (c >> 4)) * 512
              + (((c >> 3) & 1) << 8) + ((o & 31) << 3) + (c & 7);
    u16x4 pv;
    pv[0] = (short)f2bf(v[0]);
    pv[1] = (short)f2bf(v[1]);
    pv[2] = (short)f2bf(v[2]);
    pv[3] = (short)f2bf(v[3]);
    *(u16x4*)&Wb[dst] = pv;
}

// ---------------- Stage 1: QKV projection, fused 3-mat, 64-n tiles ----------------
// Grid 256 (= #CUs), 512 threads (8 waves), 1 block/CU, 142KB LDS.
// MEASURED (R12 duplicate-dispatch): qkv ~= 12us, near its ~10us traffic
// roofline. Do not further optimize.
__global__ __launch_bounds__(512, 2) void qkv_kernel(
    const float* __restrict__ x, const u16* __restrict__ Wb,
    const float* __restrict__ bq, const float* __restrict__ bk,
    const float* __restrict__ bv,
    u16* __restrict__ Qt, u16* __restrict__ Kt, u16* __restrict__ Vt) {
    const int XTS = 264;                       // 528B rows: 16B-aligned, bank-rot 4
    const int TQS = 280;                       // 560B rows: 16B-aligned
    const int TVS = 72;                        // 144B rows: 16B-aligned
    __shared__ __align__(16) u16 xT[64 * XTS];     // 33.8 KB  [n][c]
    __shared__ __align__(16) u16 tqA[64 * TQS];    // 35.8 KB  Q: [n][o]
    __shared__ __align__(16) u16 tqB[64 * TQS];    // 35.8 KB  K: [n][o]
    __shared__ __align__(16) u16 tv[256 * TVS];    // 36.9 KB  V: [o][n]

    int blk = blockIdx.x;
    int n0  = (blk & 63) << 6;
    int b   = blk >> 6;
    int tid = threadIdx.x;         // 0..511
    int lane = tid & 63;
    int w = tid >> 6;              // 0..7
    int wq = w & 3;                // o-quadrant
    int nh = w >> 2;               // n-half
    int l31 = lane & 31;
    int h = lane >> 5;

    {   // stage xT: x[b][c][n0..n0+64) fp32 -> xT[n][c] bf16 (transpose)
        int c0 = tid >> 3;                 // 0..63
        int nq = (tid & 7) << 2;           // 0..28
        const float* xb = x + ((size_t)b * C_ + c0) * N_ + n0 + nq;
        #pragma unroll
        for (int p = 0; p < 4; ++p) {
            f32x4 v0 = *(const f32x4*)(xb + (size_t)64 * N_ * p);
            f32x4 v1 = *(const f32x4*)(xb + (size_t)64 * N_ * p + 32);
            int cc = c0 + 64 * p;
            #pragma unroll
            for (int k = 0; k < 4; ++k) {
                xT[(nq + k) * XTS + cc]      = f2bf(v0[k]);
                xT[(32 + nq + k) * XTS + cc] = f2bf(v1[k]);
            }
        }
    }
    __syncthreads();

    bf16x8 xf[16];
    #pragma unroll
    for (int ks = 0; ks < 16; ++ks)
        xf[ks] = *(const bf16x8*)(&xT[(32 * nh + l31) * XTS + 16 * ks + 8 * h]);

    // ---- Q and K: D[m=n][n'=o] -> LDS [n][o] ----
    #pragma unroll
    for (int mat = 0; mat < 2; ++mat) {
        const float* bias = mat ? bk : bq;
        u16* tq = mat ? tqB : tqA;
        f32x16 acc0, acc1;
        #pragma unroll
        for (int r = 0; r < 16; ++r) { acc0[r] = 0.f; acc1[r] = 0.f; }
        const u16* wA = Wb + ((size_t)((mat * 4 + wq) * 2 + 0)) * 8192 + (size_t)lane * 8;
        const u16* wB = wA + 8192;
        #pragma unroll
        for (int ks = 0; ks < 16; ++ks) {
            bf16x8 wf0 = *(const bf16x8*)(wA + 512 * ks);
            bf16x8 wf1 = *(const bf16x8*)(wB + 512 * ks);
            acc0 = __builtin_amdgcn_mfma_f32_32x32x16_bf16(xf[ks], wf0, acc0, 0, 0, 0);
            acc1 = __builtin_amdgcn_mfma_f32_32x32x16_bf16(xf[ks], wf1, acc1, 0, 0, 0);
        }
        #pragma unroll
        for (int ot = 0; ot < 2; ++ot) {
            const f32x16& a = ot ? acc1 : acc0;
            int o = 64 * wq + 32 * ot + l31;
            float bo = bias[o];
            #pragma unroll
            for (int g = 0; g < 4; ++g)
                #pragma unroll
                for (int r = 0; r < 4; ++r) {
                    int n = 32 * nh + 8 * g + 4 * h + r;   // 0..63
                    tq[n * TQS + o] = f2bf(a[4 * g + r] + bo);
                }
        }
    }

    // ---- V: D[m=o][n'=n] -> LDS [o][n] ----
    {
        f32x16 acc0, acc1;
        #pragma unroll
        for (int r = 0; r < 16; ++r) { acc0[r] = 0.f; acc1[r] = 0.f; }
        const u16* wA = Wb + ((size_t)((2 * 4 + wq) * 2 + 0)) * 8192 + (size_t)lane * 8;
        const u16* wB = wA + 8192;
        #pragma unroll
        for (int ks = 0; ks < 16; ++ks) {
            bf16x8 wf0 = *(const bf16x8*)(wA + 512 * ks);
            bf16x8 wf1 = *(const bf16x8*)(wB + 512 * ks);
            acc0 = __builtin_amdgcn_mfma_f32_32x32x16_bf16(wf0, xf[ks], acc0, 0, 0, 0);
            acc1 = __builtin_amdgcn_mfma_f32_32x32x16_bf16(wf1, xf[ks], acc1, 0, 0, 0);
        }
        #pragma unroll
        for (int mt = 0; mt < 2; ++mt) {
            const f32x16& a = mt ? acc1 : acc0;
            #pragma unroll
            for (int g = 0; g < 4; ++g)
                #pragma unroll
                for (int r = 0; r < 4; ++r) {
                    int o = 64 * wq + 32 * mt + 8 * g + 4 * h + r;
                    tv[o * TVS + 32 * nh + l31] = f2bf(a[4 * g + r] + bv[o]);
                }
        }
    }
    __syncthreads();

    // ---- vector store phase (16B granules) ----
    {   // Q/K: thread -> row n = tid>>3 (0..63), chunks ch = (tid&7)+8i2 (128B/8 lanes)
        int n = tid >> 3;
        size_t row = ((size_t)b * N_ + n0 + n) * C_;
        #pragma unroll
        for (int i2 = 0; i2 < 4; ++i2) {
            int ch = (tid & 7) + 8 * i2;
            bf16x8 vq = *(const bf16x8*)&tqA[n * TQS + ch * 8];
            *(bf16x8*)&Qt[row + ch * 8] = vq;
            int sk = ch ^ (n & 31);   // Kt swizzle: dest chunk ch <- src o-chunk ch^(n&31)
            bf16x8 vk = *(const bf16x8*)&tqB[n * TQS + sk * 8];
            *(bf16x8*)&Kt[row + ch * 8] = vk;
        }
    }
    {   // V: thread -> n-chunk k = tid&7, rows o = (tid>>3)+64j (128B/8 lanes)
        int k = tid & 7;
        #pragma unroll
        for (int j = 0; j < 4; ++j) {
            int o = (tid >> 3) + 64 * j;
            bf16x8 vv = *(const bf16x8*)&tv[o * TVS + k * 8];
            int cd = k ^ (o & 7);     // chunk swizzle, 16B granularity, 64-aligned tile
            *(bf16x8*)&Vt[((size_t)b * C_ + o) * N_ + n0 + cd * 8] = vv;
        }
    }
}

// ---------------- Stage 2: flash attention, 4-wave blocks, 2 blocks/CU ----------------
// Grid 512 = 32 i-tiles(128) x 4 b x 4 s. 2 blocks/CU (64KB LDS each), 8 waves/CU.
// Split-phase staging: K-DMA(jt+1) issued after S^T barrier (hides under
// softmax+PV); only V-DMA latency exposed at the end-of-iter drain.
// MEASURED PLATEAU: 85us across 7 structural variants. Register budget EXACTLY
// full (128 VGPR + 128 AGPR = 2 waves/SIMD hard cap); R1 restructure spilled;
// R3 device-fence merge cost +120us; R9 K-from-L2 cost 2x.
__device__ __forceinline__ void stageK_4w(const u16* Kb, int j0, u16* ksd,
                                          int w, int lane) {
    const u16* kg = Kb + (size_t)(j0 + 16 * w) * C_ + lane * 8;
    u16* kdb = ksd + 16 * w * 256;
    #pragma unroll
    for (int rr = 0; rr < 8; ++rr)
        g2l16(kg + rr * 512, kdb + rr * 512, lane);
}
__device__ __forceinline__ void stageV_4w(const u16* Vb, int j0, u16* vsd,
                                          int w, int lane) {
    const u16* vg = Vb + (size_t)(64 * w + (lane >> 3)) * N_ + j0 + (lane & 7) * 8;
    u16* vdb = vsd + 64 * w * 64;
    #pragma unroll
    for (int rr = 0; rr < 8; ++rr)
        g2l16(vg + (size_t)8 * rr * N_, vdb + rr * 512, lane);
}

__global__ __launch_bounds__(256, 2) void attn_kernel(
    const u16* __restrict__ Qt, const u16* __restrict__ Kt,
    const u16* __restrict__ Vt, u16* __restrict__ Op,
    float* __restrict__ lArr) {
    __shared__ __align__(16) u16 Ksh[64 * 256];   // 32KB, swizzled rows
    __shared__ __align__(16) u16 Vsh[256 * 64];   // 32KB, swizzled rows

    int blk = blockIdx.x;
    int it = blk & 31;
    int b  = (blk >> 5) & 3;
    int s  = blk >> 7;                 // 0..3
    int i0 = it << 7;                  // 128-row i-tile
    int tid = threadIdx.x;
    int lane = tid & 63;
    int w = tid >> 6;                  // 0..3
    int l31 = lane & 31;
    int h = lane >> 5;

    // Q B-frags from linear Qt: n=i=l31 (wave strip i0+32w), k=c=16ks+8h+e
    bf16x8 qf[16];
    {
        const u16* qrow = Qt + ((size_t)b * N_ + i0 + 32 * w + l31) * C_ + 8 * h;
        #pragma unroll
        for (int ks = 0; ks < 16; ++ks) qf[ks] = *(const bf16x8*)(qrow + 16 * ks);
    }

    f32x16 oacc[8];
    #pragma unroll
    for (int mt = 0; mt < 8; ++mt)
        #pragma unroll
        for (int r = 0; r < 16; ++r) oacc[mt][r] = 0.f;
    float l_run = 0.f;

    const float sconst = 0.0625f * 1.44269504088896340736f;
    const u16* Kb = Kt + (size_t)b * N_ * C_;
    const u16* Vb = Vt + (size_t)b * C_ * N_;
    int jbase = s * (N_ / JS);
    const int NT = N_ / (64 * JS);     // 16

    // prologue: fill both buffers for tile 0
    stageK_4w(Kb, jbase, Ksh, w, lane);
    stageV_4w(Vb, jbase, Vsh, w, lane);
    __syncthreads();                   // drains DMA (implicit vmcnt 0)

    for (int jt = 0; jt < NT; ++jt) {
        int jn = jbase + (jt + 1) * 64;

        // S^T = K·Q^T : D[m=j][n=i]
        f32x16 st0, st1;
        #pragma unroll
        for (int r = 0; r < 16; ++r) { st0[r] = 0.f; st1[r] = 0.f; }
        __builtin_amdgcn_s_setprio(1);
        #pragma unroll
        for (int ks = 0; ks < 16; ++ks) {
            int kc = ((2 * ks + h) ^ l31) << 3;   // (32+l31)&31 == l31: same offset
            bf16x8 kf0 = *(const bf16x8*)(Ksh + l31 * 256 + kc);
            bf16x8 kf1 = *(const bf16x8*)(Ksh + (32 + l31) * 256 + kc);
            st0 = __builtin_amdgcn_mfma_f32_32x32x16_bf16(kf0, qf[ks], st0, 0, 0, 0);
            st1 = __builtin_amdgcn_mfma_f32_32x32x16_bf16(kf1, qf[ks], st1, 0, 0, 0);
        }
        __builtin_amdgcn_s_setprio(0);

        // K(jt) consumed -> issue K-DMA for jt+1; hides under softmax + PV
        __syncthreads();
        if (jt + 1 < NT) stageK_4w(Kb, jn, Ksh, w, lane);

        // softmax numerators, m=0; i = l31 per-lane, partner = lane^32
        float psum = 0.f;
        uint32_t pd[16];
        #pragma unroll
        for (int u = 0; u < 8; ++u) {
            const f32x16& stv = (u < 4) ? st0 : st1;
            int g = u & 3;
            #pragma unroll
            for (int d = 0; d < 2; ++d) {
                float p0 = fexp2(stv[4 * g + 2 * d + 0] * sconst);
                float p1 = fexp2(stv[4 * g + 2 * d + 1] * sconst);
                psum += p0 + p1;
                pd[u * 2 + d] = pkbf(p0, p1);
            }
        }
        psum += __shfl_xor(psum, 32);
        l_run += psum;

        // P: C/D -> B-operand frags via lane^32 quad exchange
        bf16x8 pf[4];
        #pragma unroll
        for (int ks2 = 0; ks2 < 4; ++ks2) {
            uint32_t oA0 = pd[4 * ks2 + 0], oA1 = pd[4 * ks2 + 1];
            uint32_t oB0 = pd[4 * ks2 + 2], oB1 = pd[4 * ks2 + 3];
            uint32_t sn0 = h ? oA0 : oB0, sn1 = h ? oA1 : oB1;
            uint32_t rc0 = (uint32_t)__shfl_xor((int)sn0, 32);
            uint32_t rc1 = (uint32_t)__shfl_xor((int)sn1, 32);
            uint32_t ow0 = h ? oB0 : oA0, ow1 = h ? oB1 : oA1;
            i32x4 fr;
            fr[0] = (int)(h ? rc0 : ow0);
            fr[1] = (int)(h ? rc1 : ow1);
            fr[2] = (int)(h ? ow0 : rc0);
            fr[3] = (int)(h ? ow1 : rc1);
            pf[ks2] = *(bf16x8*)&fr;
        }

        // O += V·P : D[m=c][n=i]; vf swizzled chunk' = (2ks2+h) ^ (l31&7)
        __builtin_amdgcn_s_setprio(1);
        #pragma unroll
        for (int ks2 = 0; ks2 < 4; ++ks2) {
            int vc = ((2 * ks2 + h) ^ (l31 & 7)) << 3;
            #pragma unroll
            for (int mt = 0; mt < 8; ++mt) {
                bf16x8 vf = *(const bf16x8*)(Vsh + (32 * mt + l31) * 64 + vc);
                oacc[mt] = __builtin_amdgcn_mfma_f32_32x32x16_bf16(vf, pf[ks2], oacc[mt], 0, 0, 0);
            }
        }
        __builtin_amdgcn_s_setprio(0);

        // V(jt) consumed -> issue V-DMA for jt+1, then drain both for next iter
        if (jt + 1 < NT) {
            __syncthreads();
            stageV_4w(Vb, jn, Vsh, w, lane);
            __syncthreads();           // drains K- and V-DMA (implicit vmcnt 0)
        }
    }

    // epilogue: unnormalized partial O + l
    int i = i0 + 32 * w + l31;
    u16* ob = Op + ((size_t)(s * B_ + b) * C_) * N_ + i;
    #pragma unroll
    for (int mt = 0; mt < 8; ++mt)
        #pragma unroll
        for (int g = 0; g < 4; ++g)
            #pragma unroll
            for (int r = 0; r < 4; ++r) {
                int c = 32 * mt + 8 * g + r + 4 * h;
                ob[(size_t)c * N_] = f2bf(oacc[mt][4 * g + r]);
            }
    if (h == 0) lArr[(size_t)(s * B_ + b) * N_ + i] = l_run;
}

// ---------------- Stage 3: merge splits + residual (vectorized) ----------------
__global__ __launch_bounds__(256) void merge_kernel(
    const float* __restrict__ x, const u16* __restrict__ Op,
    const float* __restrict__ lArr, float* __restrict__ out) {
    __shared__ float rLs[64];
    int blk = blockIdx.x;
    int cg = blk & 3;
    int ic = (blk >> 2) & 63;
    int b  = blk >> 8;
    int i0 = ic << 6;
    int tid = threadIdx.x;

    if (tid < 64) {
        float L = 0.f;
        #pragma unroll
        for (int s = 0; s < JS; ++s) L += lArr[(size_t)(s * B_ + b) * N_ + i0 + tid];
        rLs[tid] = 1.0f / L;
    }
    __syncthreads();

    int i8 = (tid & 7) << 3;                 // 8 i's
    int c  = (cg << 6) + ((tid >> 3) << 1);  // 2 c's
    f32x4 rl0 = *(const f32x4*)&rLs[i8];
    f32x4 rl1 = *(const f32x4*)&rLs[i8 + 4];

    #pragma unroll
    for (int cc = 0; cc < 2; ++cc) {
        size_t xoff = ((size_t)b * C_ + c + cc) * N_ + i0 + i8;
        float acc[8];
        #pragma unroll
        for (int e = 0; e < 8; ++e) acc[e] = 0.f;
        #pragma unroll
        for (int s = 0; s < JS; ++s) {
            bf16x8 o = *(const bf16x8*)&Op[((size_t)(s * B_ + b) * C_ + c + cc) * N_ + i0 + i8];
            #pragma unroll
            for (int e = 0; e < 8; ++e) acc[e] += bf2f((u16)o[e]);
        }
        f32x4 xv0 = *(const f32x4*)&x[xoff];
        f32x4 xv1 = *(const f32x4*)&x[xoff + 4];
        f32x4 o0, o1;
        #pragma unroll
        for (int e = 0; e < 4; ++e) {
            o0[e] = fmaf(acc[e], rl0[e], xv0[e]);
            o1[e] = fmaf(acc[e + 4], rl1[e], xv1[e]);
        }
        *(f32x4*)&out[xoff] = o0;
        *(f32x4*)&out[xoff + 4] = o1;
    }
}

extern "C" void kernel_launch(void* const* d_in, const int* in_sizes, int n_in,
                              void* d_out, int out_size, void* d_ws, size_t ws_size,
                              hipStream_t stream) {
    const float* x  = (const float*)d_in[0];
    const float* Wq = (const float*)d_in[1];
    const float* bq = (const float*)d_in[2];
    const float* Wk = (const float*)d_in[3];
    const float* bk = (const float*)d_in[4];
    const float* Wv = (const float*)d_in[5];
    const float* bv = (const float*)d_in[6];
    float* out = (float*)d_out;

    u16* Wb = (u16*)d_ws;
    u16* Qt = Wb + 3 * 65536;                     // [B][N][C] linear
    u16* Kt = Qt + (size_t)B_ * N_ * C_;          // [B][N][C] swizzled
    u16* Vt = Kt + (size_t)B_ * N_ * C_;          // [B][C][N] swizzled
    u16* Op = Vt + (size_t)B_ * N_ * C_;          // [JS][B][C][N]
    float* lArr = (float*)(Op + (size_t)JS * B_ * C_ * N_);

    wconv_kernel<<<192, 256, 0, stream>>>(Wq, Wk, Wv, Wb);
    qkv_kernel<<<256, 512, 0, stream>>>(x, Wb, bq, bk, bv, Qt, Kt, Vt);
    attn_kernel<<<512, 256, 0, stream>>>(Qt, Kt, Vt, Op, lArr);
    merge_kernel<<<1024, 256, 0, stream>>>(x, Op, lArr, out);
}